// Round 8
// baseline (46.082 us; speedup 1.0000x reference)
//
#include <hip/hip_runtime.h>
#include <cstddef>

#define NUM_TYPE 64
#define DD 256
#define NN 8192
#define GMAX 320   // max padded 32-row groups (8192/32 + 64 = 320)

typedef __bf16 bf16x8 __attribute__((ext_vector_type(8)));
typedef __bf16 bf16x4 __attribute__((ext_vector_type(4)));
typedef float f32x4 __attribute__((ext_vector_type(4)));

__device__ __forceinline__ bf16x8 cvt8v(float4 v0, float4 v1) {
  bf16x8 h;
  h[0] = (__bf16)v0.x; h[1] = (__bf16)v0.y; h[2] = (__bf16)v0.z; h[3] = (__bf16)v0.w;
  h[4] = (__bf16)v1.x; h[5] = (__bf16)v1.y; h[6] = (__bf16)v1.z; h[7] = (__bf16)v1.w;
  return h;
}

__device__ __forceinline__ bf16x8 cvt8(const float* p) {
  float4 v0 = *reinterpret_cast<const float4*>(p);
  float4 v1 = *reinterpret_cast<const float4*>(p + 4);
  return cvt8v(v0, v1);
}

__device__ __forceinline__ float tanh_fast(float x) {
  float xc = fminf(fmaxf(x, -15.f), 15.f);
  float e = __expf(2.f * xc);
  return (e - 1.f) / (e + 1.f);
}

// --- Kernel 1: packB (blocks 0..64) + perm/poff/gmap (block 65) ----------
// Lp/Wp fragment layout: frag(cg,kc) = 64 lanes x 8 bf16; lane l holds
// col cg*16+(l&15), k = kc*32+(l>>4)*8 .. +8. One frag = 1KB contiguous.
__global__ __launch_bounds__(256) void packB_kernel(
    const int* __restrict__ bi,
    const float* __restrict__ layer1,
    const float* __restrict__ W,
    int* __restrict__ type_off,
    int* __restrict__ poff,
    int* __restrict__ gmap,
    int* __restrict__ perm,
    __bf16* __restrict__ Lp,
    __bf16* __restrict__ Wp) {
  const int b = blockIdx.x;
  const int tid = threadIdx.x;

  if (b == 65) {
    // ---- perm build (256 thr, per-wave histograms) + poff/gmap ----
    __shared__ int wcnt[4][NUM_TYPE];
    __shared__ int wbase[4][NUM_TYPE];
    __shared__ int tstart[NUM_TYPE];
    const int w = tid >> 6;
    ((int*)wcnt)[tid] = 0;               // 4*64 == 256
    __syncthreads();
#pragma unroll
    for (int r = 0; r < 32; ++r) {
      int v = bi[r * 256 + tid];
      atomicAdd(&wcnt[w][v], 1);
    }
    __syncthreads();
    if (tid < NUM_TYPE) {
      int s = 0;
#pragma unroll
      for (int ww = 0; ww < 4; ++ww) { wbase[ww][tid] = s; s += wcnt[ww][tid]; }
      wcnt[0][tid] = s;                  // per-type total
    }
    __syncthreads();
    if (tid == 0) {
      int s = 0, p = 0;
      for (int t = 0; t < NUM_TYPE; ++t) {
        int c = wcnt[0][t];
        tstart[t] = s; type_off[t] = s; s += c;
        poff[t] = p;
        int ngr = (c + 31) >> 5;
        for (int j = 0; j < ngr; ++j) gmap[(p >> 5) + j] = t;
        p += ngr * 32;
      }
      type_off[NUM_TYPE] = s;
      poff[NUM_TYPE] = p;
      for (int g = p >> 5; g < GMAX; ++g) gmap[g] = -1;
    }
    __syncthreads();
    if (tid < NUM_TYPE) {
      int bb = tstart[tid];
#pragma unroll
      for (int ww = 0; ww < 4; ++ww) wbase[ww][tid] += bb;
    }
    __syncthreads();
#pragma unroll
    for (int r = 0; r < 32; ++r) {
      int i = r * 256 + tid;
      int v = bi[i];
      int p = atomicAdd(&wbase[w][v], 1);
      perm[p] = i;
    }
    return;
  }

  // ---- pack blocks: b<64 -> L[b]; b==64 -> W ----
  const float* src = (b < 64) ? layer1 + (size_t)b * DD * DD : W;
  __bf16* dst = (b < 64) ? Lp + (size_t)b * 16 * 8 * 512 : Wp;
  const int lane = tid & 63;
  const int wv = tid >> 6;
  const int lrow = lane & 15;
  const int lk = (lane >> 4) * 8;
#pragma unroll
  for (int it = 0; it < 32; ++it) {
    const int frag = it * 4 + wv;        // 0..127
    const int cg = frag >> 3;
    const int kc = frag & 7;
    const float* p = src + (size_t)(cg * 16 + lrow) * DD + kc * 32 + lk;
    bf16x8 h = cvt8(p);
    *reinterpret_cast<bf16x8*>(dst + ((size_t)frag * 64 + lane) * 8) = h;
  }
}

// --- Kernel 2: packA — gather desc rows in perm order, fragment-pack -----
__global__ __launch_bounds__(256) void packA_kernel(
    const float* __restrict__ desc,
    const int* __restrict__ type_off,
    const int* __restrict__ poff,
    const int* __restrict__ gmap,
    const int* __restrict__ perm,
    __bf16* __restrict__ Ap) {
  const int g = blockIdx.x;              // padded 32-row group
  const int t = gmap[g];
  if (t < 0) return;
  const int off = type_off[t];
  const int cnt = type_off[t + 1] - off;
  const int base = g * 32 - poff[t];     // local row base within type

  __shared__ __bf16 tile[32][264];       // +8 pad: bank-spread reads
  const int tid = threadIdx.x;
  const int row = tid >> 3;              // 0..31
  const int seg = tid & 7;               // 0..7 (32 floats each)
  const int lr = base + row;
  const int s = (lr < cnt) ? perm[off + lr] : -1;
  if (s >= 0) {
    const float4* srcp = reinterpret_cast<const float4*>(desc + (size_t)s * DD + seg * 32);
#pragma unroll
    for (int j = 0; j < 8; ++j) {
      float4 v = srcp[j];
      bf16x4 h;
      h[0] = (__bf16)v.x; h[1] = (__bf16)v.y; h[2] = (__bf16)v.z; h[3] = (__bf16)v.w;
      *reinterpret_cast<bf16x4*>(&tile[row][seg * 32 + j * 4]) = h;
    }
  } else {
#pragma unroll
    for (int j = 0; j < 8; ++j)
      *reinterpret_cast<bf16x4*>(&tile[row][seg * 32 + j * 4]) = bf16x4{};
  }
  __syncthreads();

  const int lane = tid & 63;
  const int wv = tid >> 6;
  const int lrow = lane & 15;
  const int lk = (lane >> 4) * 8;
#pragma unroll
  for (int it = 0; it < 4; ++it) {
    const int frag = it * 4 + wv;        // 0..15: (h,kc)
    const int h = frag >> 3;
    const int kc = frag & 7;
    bf16x8 v = *reinterpret_cast<const bf16x8*>(&tile[h * 16 + lrow][kc * 32 + lk]);
    *reinterpret_cast<bf16x8*>(Ap + (((size_t)(g * 2 + h) * 8 + kc) * 64 + lane) * 8) = v;
  }
}

// --- Kernel 3: GEMM on fragment-packed operands — all loads coalesced ----
__global__ __launch_bounds__(256, 2) void gemm_packed(
    const __bf16* __restrict__ Ap,
    const __bf16* __restrict__ Lp,
    const __bf16* __restrict__ Wp,
    const float* __restrict__ bias,
    const int* __restrict__ type_off,
    const int* __restrict__ poff,
    const int* __restrict__ perm,
    float* __restrict__ out) {
  const int bid  = blockIdx.x;
  const int xcd  = bid & 7;
  const int k    = bid >> 3;
  const int tloc = k >> 3;
  const int slot = k & 7;
  const int t    = xcd + 8 * tloc;
  const int cb   = slot & 1;
  const int zz   = slot >> 1;

  const int off = type_off[t];
  const int cnt = type_off[t + 1] - off;
  if (cnt <= 0) return;
  const int wave = threadIdx.x >> 6;
  const int lane = threadIdx.x & 63;
  const int l15 = lane & 15;
  const int lg = lane >> 4;

  const int cg0 = cb * 8 + wave * 2;       // col16 group
  const int cn0 = cb * 128 + wave * 32 + l15;
  const int cn1 = cn0 + 16;
  const float bv0 = bias[cn0];
  const float bv1 = bias[cn1];

  const bf16x8* Ap8 = reinterpret_cast<const bf16x8*>(Ap);
  const bf16x8* Lp8 = reinterpret_cast<const bf16x8*>(Lp) + ((size_t)(t * 16 + cg0) * 8) * 64 + lane;
  const bf16x8* Wp8 = reinterpret_cast<const bf16x8*>(Wp) + ((size_t)cg0 * 8) * 64 + lane;
  const int pbase16 = poff[t] >> 4;

  for (int mt = zz; mt * 32 < cnt; mt += 4) {
    const int r0 = mt * 32 + l15;
    const int r1 = r0 + 16;
    const int s0 = (r0 < cnt) ? perm[off + r0] : -1;
    const int s1 = (r1 < cnt) ? perm[off + r1] : -1;
    const size_t rt0 = pbase16 + mt * 2;

    f32x4 accL[2][2] = {{{0.f,0.f,0.f,0.f},{0.f,0.f,0.f,0.f}},
                        {{0.f,0.f,0.f,0.f},{0.f,0.f,0.f,0.f}}};
    f32x4 accW[2][2] = {{{0.f,0.f,0.f,0.f},{0.f,0.f,0.f,0.f}},
                        {{0.f,0.f,0.f,0.f},{0.f,0.f,0.f,0.f}}};

#pragma unroll
    for (int kc = 0; kc < 8; ++kc) {
      bf16x8 af0 = Ap8[(rt0 * 8 + kc) * 64 + lane];
      bf16x8 af1 = Ap8[((rt0 + 1) * 8 + kc) * 64 + lane];
      bf16x8 bL0 = Lp8[(size_t)kc * 64];
      bf16x8 bL1 = Lp8[(size_t)(8 + kc) * 64];
      bf16x8 bW0 = Wp8[(size_t)kc * 64];
      bf16x8 bW1 = Wp8[(size_t)(8 + kc) * 64];
      accL[0][0] = __builtin_amdgcn_mfma_f32_16x16x32_bf16(af0, bL0, accL[0][0], 0, 0, 0);
      accL[0][1] = __builtin_amdgcn_mfma_f32_16x16x32_bf16(af0, bL1, accL[0][1], 0, 0, 0);
      accL[1][0] = __builtin_amdgcn_mfma_f32_16x16x32_bf16(af1, bL0, accL[1][0], 0, 0, 0);
      accL[1][1] = __builtin_amdgcn_mfma_f32_16x16x32_bf16(af1, bL1, accL[1][1], 0, 0, 0);
      accW[0][0] = __builtin_amdgcn_mfma_f32_16x16x32_bf16(af0, bW0, accW[0][0], 0, 0, 0);
      accW[0][1] = __builtin_amdgcn_mfma_f32_16x16x32_bf16(af0, bW1, accW[0][1], 0, 0, 0);
      accW[1][0] = __builtin_amdgcn_mfma_f32_16x16x32_bf16(af1, bW0, accW[1][0], 0, 0, 0);
      accW[1][1] = __builtin_amdgcn_mfma_f32_16x16x32_bf16(af1, bW1, accW[1][1], 0, 0, 0);
    }

    // epilogue: C layout row = lg*4 + i (within 16), col = l15
#pragma unroll
    for (int m = 0; m < 2; ++m) {
      const int sFrag = m ? s1 : s0;
#pragma unroll
      for (int i = 0; i < 4; ++i) {
        const int sv = __shfl(sFrag, lg * 4 + i, 64);
        if (sv >= 0) {
          float* op = out + (size_t)sv * DD;
          __builtin_nontemporal_store(tanh_fast(accL[m][0][i]) + accW[m][0][i] + bv0, op + cn0);
          __builtin_nontemporal_store(tanh_fast(accL[m][1][i]) + accW[m][1][i] + bv1, op + cn1);
        }
      }
    }
  }
}

// --- Fallback (round-7 proven): fp32 loads, B hoisted, inline cvt --------
__global__ __launch_bounds__(1024) void build_perm_kernel(
    const int* __restrict__ bi, int* __restrict__ type_off, int* __restrict__ perm) {
  __shared__ int wcnt[16][NUM_TYPE];
  __shared__ int wbase[16][NUM_TYPE];
  __shared__ int base[NUM_TYPE];
  const int tid = threadIdx.x;
  const int w = tid >> 6;
  for (int i = tid; i < 16 * NUM_TYPE; i += 1024) ((int*)wcnt)[i] = 0;
  __syncthreads();
  int myv[8];
#pragma unroll
  for (int rnd = 0; rnd < 8; ++rnd) {
    int v = bi[rnd * 1024 + tid];
    myv[rnd] = v;
    atomicAdd(&wcnt[w][v], 1);
  }
  __syncthreads();
  if (tid < NUM_TYPE) {
    int s = 0;
#pragma unroll
    for (int ww = 0; ww < 16; ++ww) { wbase[ww][tid] = s; s += wcnt[ww][tid]; }
    base[tid] = s;
  }
  __syncthreads();
  if (tid == 0) {
    int s = 0;
    for (int t = 0; t < NUM_TYPE; ++t) { int c = base[t]; base[t] = s; type_off[t] = s; s += c; }
    type_off[NUM_TYPE] = s;
  }
  __syncthreads();
  if (tid < NUM_TYPE) {
    int b = base[tid];
#pragma unroll
    for (int ww = 0; ww < 16; ++ww) wbase[ww][tid] += b;
  }
  __syncthreads();
#pragma unroll
  for (int rnd = 0; rnd < 8; ++rnd) {
    int v = myv[rnd];
    int p = atomicAdd(&wbase[w][v], 1);
    perm[p] = rnd * 1024 + tid;
  }
}

__global__ __launch_bounds__(256, 2) void fused_kernel_f32(
    const float* __restrict__ desc,
    const float* __restrict__ layer1,
    const float* __restrict__ W,
    const float* __restrict__ bias,
    const int* __restrict__ type_off,
    const int* __restrict__ perm,
    float* __restrict__ out) {
  const int bid  = blockIdx.x;
  const int xcd  = bid & 7;
  const int k    = bid >> 3;
  const int tloc = k >> 3;
  const int slot = k & 7;
  const int t    = xcd + 8 * tloc;
  const int cb   = slot & 1;
  const int zz   = slot >> 1;

  const int off = type_off[t];
  const int cnt = type_off[t + 1] - off;
  const int wave = threadIdx.x >> 6;
  const int lane = threadIdx.x & 63;
  const int l15 = lane & 15;
  const int lg = lane >> 4;

  const int colbase = cb * 128 + wave * 32;
  const int cn0 = colbase + l15;
  const int cn1 = cn0 + 16;

  const float* bl0 = layer1 + ((size_t)t * DD + cn0) * DD + lg * 8;
  const float* bl1 = layer1 + ((size_t)t * DD + cn1) * DD + lg * 8;
  const float* bw0 = W + (size_t)cn0 * DD + lg * 8;
  const float* bw1 = W + (size_t)cn1 * DD + lg * 8;
  const float bv0 = bias[cn0];
  const float bv1 = bias[cn1];

  bf16x8 Bl0[8], Bl1[8], Bw0[8], Bw1[8];
#pragma unroll
  for (int kc = 0; kc < 8; ++kc) {
    Bl0[kc] = cvt8(bl0 + kc * 32);
    Bl1[kc] = cvt8(bl1 + kc * 32);
    Bw0[kc] = cvt8(bw0 + kc * 32);
    Bw1[kc] = cvt8(bw1 + kc * 32);
  }

  for (int mt = zz; mt * 32 < cnt; mt += 4) {
    const int r0 = mt * 32 + l15;
    const int r1 = r0 + 16;
    const int s0 = (r0 < cnt) ? perm[off + r0] : -1;
    const int s1 = (r1 < cnt) ? perm[off + r1] : -1;
    const float* a0 = desc + (size_t)(s0 < 0 ? 0 : s0) * DD + lg * 8;
    const float* a1 = desc + (size_t)(s1 < 0 ? 0 : s1) * DD + lg * 8;

    bf16x8 Af0[8], Af1[8];
#pragma unroll
    for (int kc = 0; kc < 8; ++kc) {
      Af0[kc] = cvt8(a0 + kc * 32);
      Af1[kc] = cvt8(a1 + kc * 32);
    }

    f32x4 accL[2][2] = {{{0.f,0.f,0.f,0.f},{0.f,0.f,0.f,0.f}},
                        {{0.f,0.f,0.f,0.f},{0.f,0.f,0.f,0.f}}};
    f32x4 accW[2][2] = {{{0.f,0.f,0.f,0.f},{0.f,0.f,0.f,0.f}},
                        {{0.f,0.f,0.f,0.f},{0.f,0.f,0.f,0.f}}};
#pragma unroll
    for (int kc = 0; kc < 8; ++kc) {
      accL[0][0] = __builtin_amdgcn_mfma_f32_16x16x32_bf16(Af0[kc], Bl0[kc], accL[0][0], 0, 0, 0);
      accL[0][1] = __builtin_amdgcn_mfma_f32_16x16x32_bf16(Af0[kc], Bl1[kc], accL[0][1], 0, 0, 0);
      accL[1][0] = __builtin_amdgcn_mfma_f32_16x16x32_bf16(Af1[kc], Bl0[kc], accL[1][0], 0, 0, 0);
      accL[1][1] = __builtin_amdgcn_mfma_f32_16x16x32_bf16(Af1[kc], Bl1[kc], accL[1][1], 0, 0, 0);
      accW[0][0] = __builtin_amdgcn_mfma_f32_16x16x32_bf16(Af0[kc], Bw0[kc], accW[0][0], 0, 0, 0);
      accW[0][1] = __builtin_amdgcn_mfma_f32_16x16x32_bf16(Af0[kc], Bw1[kc], accW[0][1], 0, 0, 0);
      accW[1][0] = __builtin_amdgcn_mfma_f32_16x16x32_bf16(Af1[kc], Bw0[kc], accW[1][0], 0, 0, 0);
      accW[1][1] = __builtin_amdgcn_mfma_f32_16x16x32_bf16(Af1[kc], Bw1[kc], accW[1][1], 0, 0, 0);
    }

#pragma unroll
    for (int m = 0; m < 2; ++m) {
      const int sFrag = m ? s1 : s0;
#pragma unroll
      for (int i = 0; i < 4; ++i) {
        const int sv = __shfl(sFrag, lg * 4 + i, 64);
        if (sv >= 0) {
          float* op = out + (size_t)sv * DD;
          __builtin_nontemporal_store(tanh_fast(accL[m][0][i]) + accW[m][0][i] + bv0, op + cn0);
          __builtin_nontemporal_store(tanh_fast(accL[m][1][i]) + accW[m][1][i] + bv1, op + cn1);
        }
      }
    }
  }
}

extern "C" void kernel_launch(void* const* d_in, const int* in_sizes, int n_in,
                              void* d_out, int out_size, void* d_ws, size_t ws_size,
                              hipStream_t stream) {
  const int* bi       = (const int*)d_in[0];
  const float* desc   = (const float*)d_in[1];
  const float* layer1 = (const float*)d_in[2];
  const float* W      = (const float*)d_in[3];
  const float* bias   = (const float*)d_in[4];
  float* out = (float*)d_out;

  char* ws = (char*)d_ws;
  int* type_off = (int*)(ws);                  // 65 ints   @ 0
  int* poff     = (int*)(ws + 512);            // 65 ints   @ 512
  int* gmap     = (int*)(ws + 2048);           // 320 ints  @ 2 KB
  int* perm     = (int*)(ws + 4096);           // 8192 ints @ 4 KB
  __bf16* Ap    = (__bf16*)(ws + 65536);                 // 5.00 MB
  __bf16* Lp    = (__bf16*)(ws + 65536 + 5242880);       // 8.00 MB
  __bf16* Wp    = (__bf16*)(ws + 65536 + 5242880 + 8388608); // 128 KB
  const size_t NEED = 65536 + 5242880 + 8388608 + 131072;

  if (ws_size >= NEED) {
    hipLaunchKernelGGL(packB_kernel, dim3(66), dim3(256), 0, stream,
                       bi, layer1, W, type_off, poff, gmap, perm, Lp, Wp);
    hipLaunchKernelGGL(packA_kernel, dim3(GMAX), dim3(256), 0, stream,
                       desc, type_off, poff, gmap, perm, Ap);
    hipLaunchKernelGGL(gemm_packed, dim3(512), dim3(256), 0, stream,
                       Ap, Lp, Wp, bias, type_off, poff, perm, out);
  } else {
    hipLaunchKernelGGL(build_perm_kernel, dim3(1), dim3(1024), 0, stream,
                       bi, type_off, perm);
    hipLaunchKernelGGL(fused_kernel_f32, dim3(512), dim3(256), 0, stream,
                       desc, layer1, W, bias, type_off, perm, out);
  }
}

// Round 10
// 36.413 us; speedup vs baseline: 1.2655x; 1.2655x over previous
//
#include <hip/hip_runtime.h>
#include <cstddef>

#define NUM_TYPE 64
#define DD 256
#define NN 8192

typedef __bf16 bf16x8 __attribute__((ext_vector_type(8)));
typedef __bf16 bf16x4 __attribute__((ext_vector_type(4)));
typedef float f32x4 __attribute__((ext_vector_type(4)));

__device__ __forceinline__ bf16x4 cvt4(float4 v) {
  bf16x4 h;
  h[0] = (__bf16)v.x; h[1] = (__bf16)v.y; h[2] = (__bf16)v.z; h[3] = (__bf16)v.w;
  return h;
}

__device__ __forceinline__ bf16x8 cvt8(const float* p) {
  float4 v0 = *reinterpret_cast<const float4*>(p);
  float4 v1 = *reinterpret_cast<const float4*>(p + 4);
  bf16x8 h;
  h[0] = (__bf16)v0.x; h[1] = (__bf16)v0.y; h[2] = (__bf16)v0.z; h[3] = (__bf16)v0.w;
  h[4] = (__bf16)v1.x; h[5] = (__bf16)v1.y; h[6] = (__bf16)v1.z; h[7] = (__bf16)v1.w;
  return h;
}

__device__ __forceinline__ float tanh_fast(float x) {
  float xc = fminf(fmaxf(x, -15.f), 15.f);
  float e = __expf(2.f * xc);
  return (e - 1.f) / (e + 1.f);
}

// --- Kernel 1: prep — packB via LDS (blocks 0..519) + perm (block 520) ---
// Fragment layout: frag(cg,kc) = 64 lanes x 8 bf16 (1 KB, contiguous);
// lane l holds col cg*16+(l&15), k = kc*32+(l>>4)*8..+8.
__global__ __launch_bounds__(256) void prep_kernel(
    const int* __restrict__ bi,
    const float* __restrict__ layer1,
    const float* __restrict__ W,
    int* __restrict__ type_off,
    int* __restrict__ perm,
    __bf16* __restrict__ Lp,
    __bf16* __restrict__ Wp) {
  const int b = blockIdx.x;
  const int tid = threadIdx.x;

  if (b == 520) {
    __shared__ int wcnt[4][NUM_TYPE];
    __shared__ int wbase[4][NUM_TYPE];
    __shared__ int tstart[NUM_TYPE];
    const int w = tid >> 6;
    ((int*)wcnt)[tid] = 0;               // 4*64 == 256
    __syncthreads();
#pragma unroll
    for (int r = 0; r < 32; ++r) {
      int v = bi[r * 256 + tid];
      atomicAdd(&wcnt[w][v], 1);
    }
    __syncthreads();
    if (tid < NUM_TYPE) {
      int s = 0;
#pragma unroll
      for (int ww = 0; ww < 4; ++ww) { wbase[ww][tid] = s; s += wcnt[ww][tid]; }
      wcnt[0][tid] = s;                  // per-type total
    }
    __syncthreads();
    if (tid == 0) {
      int s = 0;
      for (int t = 0; t < NUM_TYPE; ++t) {
        int c = wcnt[0][t];
        tstart[t] = s; type_off[t] = s; s += c;
      }
      type_off[NUM_TYPE] = s;
    }
    __syncthreads();
    if (tid < NUM_TYPE) {
      int bb = tstart[tid];
#pragma unroll
      for (int ww = 0; ww < 4; ++ww) wbase[ww][tid] += bb;
    }
    __syncthreads();
#pragma unroll
    for (int r = 0; r < 32; ++r) {
      int i = r * 256 + tid;
      int v = bi[i];
      int p = atomicAdd(&wbase[w][v], 1);
      perm[p] = i;
    }
    return;
  }

  const int lane = tid & 63;
  const int wv = tid >> 6;
  const int l15 = lane & 15;
  const int lg = lane >> 4;

  const float* src;
  __bf16* dst;
  int part;
  if (b < 512) {
    const int xcd = b & 7, jj = b >> 3;
    const int t = xcd + 8 * (jj >> 3);
    part = jj & 7;
    src = layer1 + (size_t)t * DD * DD;
    dst = Lp + (size_t)t * 128 * 512;    // 128 frags x 512 elems
  } else {
    part = b - 512;
    src = W;
    dst = Wp;
  }

  __shared__ __bf16 tile[32][264];       // 528 B stride: uniform banks
  // stage 32 rows, one full row per wave-instruction (fully coalesced)
#pragma unroll
  for (int i = 0; i < 8; ++i) {
    const int rl = wv * 8 + i;
    const int row = part * 32 + rl;
    float4 v = reinterpret_cast<const float4*>(src + (size_t)row * DD)[lane];
    *reinterpret_cast<bf16x4*>(&tile[rl][lane * 4]) = cvt4(v);
  }
  __syncthreads();
  // extract 4 fragments per wave, store coalesced (1 KB each)
#pragma unroll
  for (int i = 0; i < 4; ++i) {
    const int it = wv * 4 + i;           // 0..15
    const int cgl = it >> 3;
    const int kc = it & 7;
    bf16x8 v = *reinterpret_cast<const bf16x8*>(&tile[cgl * 16 + l15][kc * 32 + lg * 8]);
    const int frag = part * 16 + it;
    *reinterpret_cast<bf16x8*>(dst + ((size_t)frag * 64 + lane) * 8) = v;
  }
}

// --- Kernel 2: GEMM — A via cooperative LDS stage, B packed/coalesced ----
__global__ __launch_bounds__(256, 2) void gemm_packed(
    const float* __restrict__ desc,
    const __bf16* __restrict__ Lp,
    const __bf16* __restrict__ Wp,
    const float* __restrict__ bias,
    const int* __restrict__ type_off,
    const int* __restrict__ perm,
    float* __restrict__ out) {
  const int bid  = blockIdx.x;
  const int xcd  = bid & 7;
  const int k    = bid >> 3;
  const int tloc = k >> 3;
  const int slot = k & 7;
  const int t    = xcd + 8 * tloc;
  const int cb   = slot & 1;
  const int zz   = slot >> 1;

  const int off = type_off[t];
  const int cnt = type_off[t + 1] - off;
  if (cnt <= 0) return;
  const int wave = threadIdx.x >> 6;
  const int lane = threadIdx.x & 63;
  const int l15 = lane & 15;
  const int lg = lane >> 4;

  const int cg0 = cb * 8 + wave * 2;
  const int cn0 = cb * 128 + wave * 32 + l15;
  const int cn1 = cn0 + 16;
  const float bv0 = bias[cn0];
  const float bv1 = bias[cn1];

  // B hoist: 32 coalesced 1 KB loads (single-lane-stride)
  const bf16x8* Lp8 = reinterpret_cast<const bf16x8*>(Lp) + ((size_t)(t * 16 + cg0) * 8) * 64 + lane;
  const bf16x8* Wp8 = reinterpret_cast<const bf16x8*>(Wp) + ((size_t)cg0 * 8) * 64 + lane;
  bf16x8 Bl0[8], Bl1[8], Bw0[8], Bw1[8];
#pragma unroll
  for (int kc = 0; kc < 8; ++kc) {
    Bl0[kc] = Lp8[(size_t)kc * 64];
    Bl1[kc] = Lp8[(size_t)(8 + kc) * 64];
    Bw0[kc] = Wp8[(size_t)kc * 64];
    Bw1[kc] = Wp8[(size_t)(8 + kc) * 64];
  }

  __shared__ __bf16 tile[32][264];
  bool first = true;
  for (int mt = zz; mt * 32 < cnt; mt += 4) {
    if (!first) __syncthreads();         // protect tile overwrite
    first = false;
    // cooperative A stage: row-per-instruction coalesced gather
#pragma unroll
    for (int i = 0; i < 8; ++i) {
      const int rl = wave * 8 + i;
      const int r = mt * 32 + rl;
      if (r < cnt) {
        const int s = perm[off + r];
        float4 v = reinterpret_cast<const float4*>(desc + (size_t)s * DD)[lane];
        *reinterpret_cast<bf16x4*>(&tile[rl][lane * 4]) = cvt4(v);
      } else {
        *reinterpret_cast<bf16x4*>(&tile[rl][lane * 4]) = bf16x4{};
      }
    }
    __syncthreads();

    const int r0 = mt * 32 + l15;
    const int r1 = r0 + 16;
    const int s0 = (r0 < cnt) ? perm[off + r0] : -1;
    const int s1 = (r1 < cnt) ? perm[off + r1] : -1;

    f32x4 accL[2][2] = {{{0.f,0.f,0.f,0.f},{0.f,0.f,0.f,0.f}},
                        {{0.f,0.f,0.f,0.f},{0.f,0.f,0.f,0.f}}};
    f32x4 accW[2][2] = {{{0.f,0.f,0.f,0.f},{0.f,0.f,0.f,0.f}},
                        {{0.f,0.f,0.f,0.f},{0.f,0.f,0.f,0.f}}};

#pragma unroll
    for (int kc = 0; kc < 8; ++kc) {
      bf16x8 af0 = *reinterpret_cast<const bf16x8*>(&tile[l15][kc * 32 + lg * 8]);
      bf16x8 af1 = *reinterpret_cast<const bf16x8*>(&tile[16 + l15][kc * 32 + lg * 8]);
      accL[0][0] = __builtin_amdgcn_mfma_f32_16x16x32_bf16(af0, Bl0[kc], accL[0][0], 0, 0, 0);
      accL[0][1] = __builtin_amdgcn_mfma_f32_16x16x32_bf16(af0, Bl1[kc], accL[0][1], 0, 0, 0);
      accL[1][0] = __builtin_amdgcn_mfma_f32_16x16x32_bf16(af1, Bl0[kc], accL[1][0], 0, 0, 0);
      accL[1][1] = __builtin_amdgcn_mfma_f32_16x16x32_bf16(af1, Bl1[kc], accL[1][1], 0, 0, 0);
      accW[0][0] = __builtin_amdgcn_mfma_f32_16x16x32_bf16(af0, Bw0[kc], accW[0][0], 0, 0, 0);
      accW[0][1] = __builtin_amdgcn_mfma_f32_16x16x32_bf16(af0, Bw1[kc], accW[0][1], 0, 0, 0);
      accW[1][0] = __builtin_amdgcn_mfma_f32_16x16x32_bf16(af1, Bw0[kc], accW[1][0], 0, 0, 0);
      accW[1][1] = __builtin_amdgcn_mfma_f32_16x16x32_bf16(af1, Bw1[kc], accW[1][1], 0, 0, 0);
    }

    // epilogue: C layout row = lg*4 + i (within 16), col = l15
#pragma unroll
    for (int m = 0; m < 2; ++m) {
      const int sFrag = m ? s1 : s0;
#pragma unroll
      for (int i = 0; i < 4; ++i) {
        const int sv = __shfl(sFrag, lg * 4 + i, 64);
        if (sv >= 0) {
          float* op = out + (size_t)sv * DD;
          __builtin_nontemporal_store(tanh_fast(accL[m][0][i]) + accW[m][0][i] + bv0, op + cn0);
          __builtin_nontemporal_store(tanh_fast(accL[m][1][i]) + accW[m][1][i] + bv1, op + cn1);
        }
      }
    }
  }
}

// --- Fallback (round-7 proven): fp32 loads, B hoisted, inline cvt --------
__global__ __launch_bounds__(1024) void build_perm_kernel(
    const int* __restrict__ bi, int* __restrict__ type_off, int* __restrict__ perm) {
  __shared__ int wcnt[16][NUM_TYPE];
  __shared__ int wbase[16][NUM_TYPE];
  __shared__ int base[NUM_TYPE];
  const int tid = threadIdx.x;
  const int w = tid >> 6;
  for (int i = tid; i < 16 * NUM_TYPE; i += 1024) ((int*)wcnt)[i] = 0;
  __syncthreads();
  int myv[8];
#pragma unroll
  for (int rnd = 0; rnd < 8; ++rnd) {
    int v = bi[rnd * 1024 + tid];
    myv[rnd] = v;
    atomicAdd(&wcnt[w][v], 1);
  }
  __syncthreads();
  if (tid < NUM_TYPE) {
    int s = 0;
#pragma unroll
    for (int ww = 0; ww < 16; ++ww) { wbase[ww][tid] = s; s += wcnt[ww][tid]; }
    base[tid] = s;
  }
  __syncthreads();
  if (tid == 0) {
    int s = 0;
    for (int t = 0; t < NUM_TYPE; ++t) { int c = base[t]; base[t] = s; type_off[t] = s; s += c; }
    type_off[NUM_TYPE] = s;
  }
  __syncthreads();
  if (tid < NUM_TYPE) {
    int b = base[tid];
#pragma unroll
    for (int ww = 0; ww < 16; ++ww) wbase[ww][tid] += b;
  }
  __syncthreads();
#pragma unroll
  for (int rnd = 0; rnd < 8; ++rnd) {
    int v = myv[rnd];
    int p = atomicAdd(&wbase[w][v], 1);
    perm[p] = rnd * 1024 + tid;
  }
}

__global__ __launch_bounds__(256, 2) void fused_kernel_f32(
    const float* __restrict__ desc,
    const float* __restrict__ layer1,
    const float* __restrict__ W,
    const float* __restrict__ bias,
    const int* __restrict__ type_off,
    const int* __restrict__ perm,
    float* __restrict__ out) {
  const int bid  = blockIdx.x;
  const int xcd  = bid & 7;
  const int k    = bid >> 3;
  const int tloc = k >> 3;
  const int slot = k & 7;
  const int t    = xcd + 8 * tloc;
  const int cb   = slot & 1;
  const int zz   = slot >> 1;

  const int off = type_off[t];
  const int cnt = type_off[t + 1] - off;
  const int wave = threadIdx.x >> 6;
  const int lane = threadIdx.x & 63;
  const int l15 = lane & 15;
  const int lg = lane >> 4;

  const int colbase = cb * 128 + wave * 32;
  const int cn0 = colbase + l15;
  const int cn1 = cn0 + 16;

  const float* bl0 = layer1 + ((size_t)t * DD + cn0) * DD + lg * 8;
  const float* bl1 = layer1 + ((size_t)t * DD + cn1) * DD + lg * 8;
  const float* bw0 = W + (size_t)cn0 * DD + lg * 8;
  const float* bw1 = W + (size_t)cn1 * DD + lg * 8;
  const float bv0 = bias[cn0];
  const float bv1 = bias[cn1];

  bf16x8 Bl0[8], Bl1[8], Bw0[8], Bw1[8];
#pragma unroll
  for (int kc = 0; kc < 8; ++kc) {
    Bl0[kc] = cvt8(bl0 + kc * 32);
    Bl1[kc] = cvt8(bl1 + kc * 32);
    Bw0[kc] = cvt8(bw0 + kc * 32);
    Bw1[kc] = cvt8(bw1 + kc * 32);
  }

  for (int mt = zz; mt * 32 < cnt; mt += 4) {
    const int r0 = mt * 32 + l15;
    const int r1 = r0 + 16;
    const int s0 = (r0 < cnt) ? perm[off + r0] : -1;
    const int s1 = (r1 < cnt) ? perm[off + r1] : -1;
    const float* a0 = desc + (size_t)(s0 < 0 ? 0 : s0) * DD + lg * 8;
    const float* a1 = desc + (size_t)(s1 < 0 ? 0 : s1) * DD + lg * 8;

    bf16x8 Af0[8], Af1[8];
#pragma unroll
    for (int kc = 0; kc < 8; ++kc) {
      Af0[kc] = cvt8(a0 + kc * 32);
      Af1[kc] = cvt8(a1 + kc * 32);
    }

    f32x4 accL[2][2] = {{{0.f,0.f,0.f,0.f},{0.f,0.f,0.f,0.f}},
                        {{0.f,0.f,0.f,0.f},{0.f,0.f,0.f,0.f}}};
    f32x4 accW[2][2] = {{{0.f,0.f,0.f,0.f},{0.f,0.f,0.f,0.f}},
                        {{0.f,0.f,0.f,0.f},{0.f,0.f,0.f,0.f}}};
#pragma unroll
    for (int kc = 0; kc < 8; ++kc) {
      accL[0][0] = __builtin_amdgcn_mfma_f32_16x16x32_bf16(Af0[kc], Bl0[kc], accL[0][0], 0, 0, 0);
      accL[0][1] = __builtin_amdgcn_mfma_f32_16x16x32_bf16(Af0[kc], Bl1[kc], accL[0][1], 0, 0, 0);
      accL[1][0] = __builtin_amdgcn_mfma_f32_16x16x32_bf16(Af1[kc], Bl0[kc], accL[1][0], 0, 0, 0);
      accL[1][1] = __builtin_amdgcn_mfma_f32_16x16x32_bf16(Af1[kc], Bl1[kc], accL[1][1], 0, 0, 0);
      accW[0][0] = __builtin_amdgcn_mfma_f32_16x16x32_bf16(Af0[kc], Bw0[kc], accW[0][0], 0, 0, 0);
      accW[0][1] = __builtin_amdgcn_mfma_f32_16x16x32_bf16(Af0[kc], Bw1[kc], accW[0][1], 0, 0, 0);
      accW[1][0] = __builtin_amdgcn_mfma_f32_16x16x32_bf16(Af1[kc], Bw0[kc], accW[1][0], 0, 0, 0);
      accW[1][1] = __builtin_amdgcn_mfma_f32_16x16x32_bf16(Af1[kc], Bw1[kc], accW[1][1], 0, 0, 0);
    }

#pragma unroll
    for (int m = 0; m < 2; ++m) {
      const int sFrag = m ? s1 : s0;
#pragma unroll
      for (int i = 0; i < 4; ++i) {
        const int sv = __shfl(sFrag, lg * 4 + i, 64);
        if (sv >= 0) {
          float* op = out + (size_t)sv * DD;
          __builtin_nontemporal_store(tanh_fast(accL[m][0][i]) + accW[m][0][i] + bv0, op + cn0);
          __builtin_nontemporal_store(tanh_fast(accL[m][1][i]) + accW[m][1][i] + bv1, op + cn1);
        }
      }
    }
  }
}

extern "C" void kernel_launch(void* const* d_in, const int* in_sizes, int n_in,
                              void* d_out, int out_size, void* d_ws, size_t ws_size,
                              hipStream_t stream) {
  const int* bi       = (const int*)d_in[0];
  const float* desc   = (const float*)d_in[1];
  const float* layer1 = (const float*)d_in[2];
  const float* W      = (const float*)d_in[3];
  const float* bias   = (const float*)d_in[4];
  float* out = (float*)d_out;

  char* ws = (char*)d_ws;
  int* type_off = (int*)(ws);                      // 65 ints   @ 0
  int* perm     = (int*)(ws + 4096);               // 8192 ints @ 4 KB
  __bf16* Lp    = (__bf16*)(ws + 65536);           // 8 MB
  __bf16* Wp    = (__bf16*)(ws + 65536 + 8388608); // 128 KB
  const size_t NEED = 65536 + 8388608 + 131072;

  if (ws_size >= NEED) {
    hipLaunchKernelGGL(prep_kernel, dim3(521), dim3(256), 0, stream,
                       bi, layer1, W, type_off, perm, Lp, Wp);
    hipLaunchKernelGGL(gemm_packed, dim3(512), dim3(256), 0, stream,
                       desc, Lp, Wp, bias, type_off, perm, out);
  } else {
    hipLaunchKernelGGL(build_perm_kernel, dim3(1), dim3(1024), 0, stream,
                       bi, type_off, perm);
    hipLaunchKernelGGL(fused_kernel_f32, dim3(512), dim3(256), 0, stream,
                       desc, layer1, W, bias, type_off, perm, out);
  }
}